// Round 8
// baseline (138.486 us; speedup 1.0000x reference)
//
#include <hip/hip_runtime.h>
#include <hip/hip_bf16.h>
#include <math.h>

#define D_MODEL 768
#define HEADS 12
#define DK 64
#define SEQ 2048
#define BATCH 2
#define MTOT (BATCH * SEQ)   // 4096
#define QSCALE 0.18033688011112042f   // 0.125 * log2(e): softmax in exp2 domain

using short8 = __attribute__((ext_vector_type(8))) short;
using us4    = __attribute__((ext_vector_type(4))) unsigned short;
using f32x4  = __attribute__((ext_vector_type(4))) float;

// ---------------- helpers ---------------------------------------------------
static __device__ __forceinline__ unsigned f2bf2(float x, float y) {
    __hip_bfloat162 t = __float22bfloat162_rn(float2{x, y});
    return *reinterpret_cast<unsigned*>(&t);
}
static __device__ __forceinline__ unsigned short f2bf1(float x) {
    __hip_bfloat16 t = __float2bfloat16(x);
    return *reinterpret_cast<unsigned short*>(&t);
}
static __device__ __forceinline__ float bf2f(unsigned short u) {
    unsigned v = (unsigned)u << 16;
    return __uint_as_float(v);
}
static __device__ __forceinline__ short8 cvt8(float4 a, float4 b) {
    union { unsigned u[4]; short8 s; } r;
    r.u[0] = f2bf2(a.x, a.y);
    r.u[1] = f2bf2(a.z, a.w);
    r.u[2] = f2bf2(b.x, b.y);
    r.u[3] = f2bf2(b.z, b.w);
    return r.s;
}
static __device__ __forceinline__ float fast_exp2(float x) {
#if __has_builtin(__builtin_amdgcn_exp2f)
    return __builtin_amdgcn_exp2f(x);
#else
    return __expf(x * 0.6931471805599453f);
#endif
}

static __device__ __forceinline__ void gload_lds16(const void* g, void* l) {
    __builtin_amdgcn_global_load_lds(
        (const __attribute__((address_space(1))) void*)g,
        (__attribute__((address_space(3))) void*)l, 16, 0, 0);
}

// barrier draining LDS ops only (VMEM prefetch stays in flight unless a
// register dependency already retired it)
static __device__ __forceinline__ void barrier_lgkm() {
    asm volatile("s_waitcnt lgkmcnt(0)" ::: "memory");
    __builtin_amdgcn_s_barrier();
    __builtin_amdgcn_sched_barrier(0);
}
static __device__ __forceinline__ void barrier_vm0() {
    asm volatile("s_waitcnt vmcnt(0)" ::: "memory");
    __builtin_amdgcn_s_barrier();
    __builtin_amdgcn_sched_barrier(0);
}

// ---------------- pre-pass: W[k][n] fp32 -> Wt[n][k] bf16 (4 W's fused) -----
__global__ __launch_bounds__(256) void cvt_wt_k(
    const float* __restrict__ Wq, const float* __restrict__ Wk,
    const float* __restrict__ Wv, const float* __restrict__ Wo,
    unsigned short* __restrict__ Wqt, unsigned short* __restrict__ Wkt,
    unsigned short* __restrict__ Wvt, unsigned short* __restrict__ Wot)
{
    const int z = blockIdx.z;
    const float* W = z == 0 ? Wq : z == 1 ? Wk : z == 2 ? Wv : Wo;
    unsigned short* Wt = z == 0 ? Wqt : z == 1 ? Wkt : z == 2 ? Wvt : Wot;
    __shared__ float t[32][33];
    const int n0 = blockIdx.x * 32, k0 = blockIdx.y * 32;
    const int tx = threadIdx.x & 31;
    const int ty0 = (threadIdx.x >> 5) * 4;
    #pragma unroll
    for (int j = 0; j < 4; ++j)
        t[ty0 + j][tx] = W[(size_t)(k0 + ty0 + j) * D_MODEL + n0 + tx];
    __syncthreads();
    #pragma unroll
    for (int j = 0; j < 4; ++j)
        Wt[(size_t)(n0 + ty0 + j) * D_MODEL + k0 + tx] = f2bf1(t[tx][ty0 + j]);
}

// ---------------- bf16 MFMA GEMM: 128x128 tile, BK=64, 2 bufs, unroll-2 -----
// 4 waves (2x2), per-wave 64x64 output (4x4 accs of 16x16).
// A_FP32: A fp32, reg-staged + cvt to bf16 LDS (write-late).
// else:   A bf16, staged via global_load_lds (pre-swizzled source).
template <int A_FP32, int OUT_BF16>
static __device__ __forceinline__ void gemm_body(
    const void* __restrict__ Av, const unsigned short* __restrict__ Wt,
    const float* __restrict__ bias, void* __restrict__ C, float scale,
    int brow, int bcol)
{
    __shared__ __align__(16) char gsm[65536];   // A: 0+buf*16384 ; B: 32768+buf*16384

    const int tid  = threadIdx.x;
    const int w    = tid >> 6;
    const int lane = tid & 63;
    const int g    = lane >> 4, c = lane & 15;
    const int wr   = w >> 1, wc = w & 1;

    f32x4 acc[4][4] = {};

    // hoisted read bases: row&7 == c&7 for every fragment row
    const int xc  = (c & 7) << 4;
    const int rb0 = c * 128 + ((g * 16) ^ xc);            // kstep 0
    const int rb1 = c * 128 + ((64 + g * 16) ^ xc);       // kstep 1

    // bf16 staging via gload_lds: 16KB/tile = 16 chunks of 1KB (4 per wave)
    int bsrow[4], bsoff[4], bsdst[4];
    #pragma unroll
    for (int r = 0; r < 4; ++r) {
        int phys = (w * 4 + r) * 1024 + lane * 16;
        int row  = phys >> 7;
        int slot = (phys >> 4) & 7;
        bsrow[r] = row;
        bsoff[r] = (slot ^ (row & 7)) * 8;
        bsdst[r] = (w * 4 + r) * 1024;
    }
    // fp32-A staging: thread owns row ar, 32 k-elems at ac
    const int ar = tid >> 1;
    const int ac = (tid & 1) << 5;
    int awa[4];
    #pragma unroll
    for (int i = 0; i < 4; ++i)
        awa[i] = ar * 128 + (((ac << 1) + 16 * i) ^ ((ar & 7) << 4));
    const float* Ap32 = (const float*)Av + (size_t)(brow + ar) * D_MODEL + ac;
    const unsigned short* Ap16 = (const unsigned short*)Av;

    float4 r0, r1, r2, r3, r4, r5, r6, r7;   // fp32 A in-flight regs

    auto stageB = [&](int k0, int buf) {
        #pragma unroll
        for (int r = 0; r < 4; ++r)
            gload_lds16(Wt + (size_t)(bcol + bsrow[r]) * D_MODEL + k0 + bsoff[r],
                        gsm + 32768 + buf * 16384 + bsdst[r]);
    };
    auto stageA16 = [&](int k0, int buf) {
        #pragma unroll
        for (int r = 0; r < 4; ++r)
            gload_lds16(Ap16 + (size_t)(brow + bsrow[r]) * D_MODEL + k0 + bsoff[r],
                        gsm + buf * 16384 + bsdst[r]);
    };
    auto loadA32 = [&](int k0) {
        r0 = *(const float4*)(Ap32 + k0);
        r1 = *(const float4*)(Ap32 + k0 + 4);
        r2 = *(const float4*)(Ap32 + k0 + 8);
        r3 = *(const float4*)(Ap32 + k0 + 12);
        r4 = *(const float4*)(Ap32 + k0 + 16);
        r5 = *(const float4*)(Ap32 + k0 + 20);
        r6 = *(const float4*)(Ap32 + k0 + 24);
        r7 = *(const float4*)(Ap32 + k0 + 28);
    };
    auto writeA32 = [&](int buf) {   // reg-dep wait retires B gloads issued earlier
        *(short8*)(gsm + buf * 16384 + awa[0]) = cvt8(r0, r1);
        *(short8*)(gsm + buf * 16384 + awa[1]) = cvt8(r2, r3);
        *(short8*)(gsm + buf * 16384 + awa[2]) = cvt8(r4, r5);
        *(short8*)(gsm + buf * 16384 + awa[3]) = cvt8(r6, r7);
    };

    // prologue: fill buf0
    if (A_FP32) {
        stageB(0, 0);
        loadA32(0);
        writeA32(0);
        barrier_lgkm();
    } else {
        stageA16(0, 0);
        stageB(0, 0);
        barrier_vm0();
    }

    for (int k0 = 0; k0 < D_MODEL; k0 += 128) {
        #pragma unroll
        for (int u = 0; u < 2; ++u) {
            const int kn = min(k0 + u * 64 + 64, D_MODEL - 64);   // tail dup: harmless
            if (A_FP32) {
                stageB(kn, u ^ 1);
                loadA32(kn);
            } else {
                stageA16(kn, u ^ 1);
                stageB(kn, u ^ 1);
            }
            __builtin_amdgcn_sched_barrier(0);

            __builtin_amdgcn_s_setprio(1);
            #pragma unroll
            for (int kstep = 0; kstep < 2; ++kstep) {
                const int rb = kstep ? rb1 : rb0;
                short8 af[4], bf[4];
                #pragma unroll
                for (int m = 0; m < 4; ++m)
                    af[m] = *(const short8*)(gsm + u * 16384 + wr * 8192 +
                                             m * 2048 + rb);
                #pragma unroll
                for (int n = 0; n < 4; ++n)
                    bf[n] = *(const short8*)(gsm + 32768 + u * 16384 + wc * 8192 +
                                             n * 2048 + rb);
                #pragma unroll
                for (int m = 0; m < 4; ++m)
                    #pragma unroll
                    for (int n = 0; n < 4; ++n)
                        acc[m][n] = __builtin_amdgcn_mfma_f32_16x16x32_bf16(
                                        af[m], bf[n], acc[m][n], 0, 0, 0);
            }
            __builtin_amdgcn_s_setprio(0);

            if (A_FP32) {
                writeA32(u ^ 1);
                barrier_lgkm();
            } else {
                barrier_vm0();
            }
        }
    }

    #pragma unroll
    for (int m = 0; m < 4; ++m)
        #pragma unroll
        for (int n = 0; n < 4; ++n) {
            const int col = bcol + wc * 64 + n * 16 + c;
            const float bval = bias[col];
            #pragma unroll
            for (int j = 0; j < 4; ++j) {
                const int row = brow + wr * 64 + m * 16 + g * 4 + j;
                const float val = (acc[m][n][j] + bval) * scale;
                if (OUT_BF16)
                    ((unsigned short*)C)[(size_t)row * D_MODEL + col] = f2bf1(val);
                else
                    ((float*)C)[(size_t)row * D_MODEL + col] = val;
            }
        }
}

// QKV: grid 576, XCD-chunked: per xcd 72 blocks = 3z x 4 brow x 6 bcol, bcol
// innermost so the 6 blocks sharing one fp32 A-panel run on ONE XCD.
__global__ __launch_bounds__(256) void gemm_qkv_k(
    const float* __restrict__ query, const float* __restrict__ key,
    const float* __restrict__ value,
    const unsigned short* __restrict__ Wqt, const unsigned short* __restrict__ Wkt,
    const unsigned short* __restrict__ Wvt,
    const float* __restrict__ bq, const float* __restrict__ bk,
    const float* __restrict__ bv,
    unsigned short* __restrict__ qb, unsigned short* __restrict__ kb,
    unsigned short* __restrict__ vb)
{
    const int bid = blockIdx.x;
    const int xcd = bid & 7;
    const int idx = bid >> 3;          // 0..71
    const int z   = idx / 24;
    const int rr  = idx % 24;
    const int brow = (xcd * 4 + rr / 6) * 128;
    const int bcol = (rr % 6) * 128;

    const void* A            = z == 0 ? (const void*)query : z == 1 ? (const void*)key : (const void*)value;
    const unsigned short* Wt = z == 0 ? Wqt : z == 1 ? Wkt : Wvt;
    const float* bias        = z == 0 ? bq  : z == 1 ? bk  : bv;
    unsigned short* C        = z == 0 ? qb  : z == 1 ? kb  : vb;
    gemm_body<1, 1>(A, Wt, bias, C, z == 0 ? QSCALE : 1.0f, brow, bcol);
}

__global__ __launch_bounds__(256) void gemm_o_k(
    const unsigned short* __restrict__ A, const unsigned short* __restrict__ Wt,
    const float* __restrict__ bias, float* __restrict__ C)
{
    const int bid = blockIdx.x;
    const int xcd = bid & 7;
    const int idx = bid >> 3;          // 0..23
    const int brow = (xcd * 4 + idx / 6) * 128;
    const int bcol = (idx % 6) * 128;
    gemm_body<0, 0>(A, Wt, bias, C, 1.0f, brow, bcol);
}

// ---------------- Flash attention: KV-split x2, 8 waves, 2 bufs -------------
// grid 768 (flat, XCD-chunk swizzled), 512 thr = 8 waves; wave w: q-rows
// [q0+16w, q0+16w+16), q0 = qt*128. Block handles KV tiles [half*16, half*16+16).
// Waves 0-3 stage K (gload_lds) + V (reg->LDS, pi-permuted); waves 4-7 pure
// compute (role-split -> setprio pays). Partials: o (bf16, unnormalized) + per
// row (m, l) f32; combine_k merges halves exactly.
// LDS 48KB: K: 0+buf*8192 ; V^T: 16384+buf*8192 ; P: 32768 + w*2048
__global__ __launch_bounds__(512) void attn_mfma_k(
    const unsigned short* __restrict__ q, const unsigned short* __restrict__ k,
    const unsigned short* __restrict__ v, unsigned short* __restrict__ opart,
    float* __restrict__ mlpart)
{
    __shared__ __align__(16) char sm[49152];

    const int tid  = threadIdx.x;
    const int w    = tid >> 6;
    const int lane = tid & 63;
    const int g    = lane >> 4;
    const int c    = lane & 15;

    const int bid  = blockIdx.x;
    const int swz  = (bid & 7) * 96 + (bid >> 3);
    const int qt   = swz & 15;
    const int rest = swz >> 4;         // 0..47
    const int half = rest & 1;
    const int hb   = rest >> 1;        // 0..23
    const int h    = hb % HEADS;
    const int b    = hb / HEADS;
    const int q0   = qt * 128;
    const int NT2  = 16;               // tiles per half

    // Q strip A-frags (pre-scaled by QSCALE in the projection GEMM)
    short8 qf0, qf1;
    {
        const int qrow = q0 + (w << 4) + c;
        const unsigned short* qp = q + (size_t)(b * SEQ + qrow) * D_MODEL + h * DK;
        qf0 = *(const short8*)(qp + g * 8);
        qf1 = *(const short8*)(qp + 32 + g * 8);
    }

    float m_run[4] = {-INFINITY, -INFINITY, -INFINITY, -INFINITY};
    f32x4 lacc = f32x4{0, 0, 0, 0};
    f32x4 o[4] = {f32x4{0,0,0,0}, f32x4{0,0,0,0}, f32x4{0,0,0,0}, f32x4{0,0,0,0}};
    const short8 ONES = {0x3F80, 0x3F80, 0x3F80, 0x3F80,
                         0x3F80, 0x3F80, 0x3F80, 0x3F80};

    // hoisted LDS read bases (row&7 == c&7 for K/V/P fragment rows)
    const int xc  = (c & 7) << 4;
    const int rb0 = c * 128 + ((g * 16) ^ xc);        // kstep 0
    const int rb1 = c * 128 + ((64 + g * 16) ^ xc);   // kstep 1
    const int bp0 = 32768 + w * 2048 + rb0;           // P read bases
    const int bp1 = 32768 + w * 2048 + rb1;

    // P write addresses (per reg)
    int pwa[4];
    #pragma unroll
    for (int r = 0; r < 4; ++r) {
        const int row = (g << 2) + r;
        pwa[r] = 32768 + w * 2048 + row * 128 + ((c << 3) ^ ((row & 7) << 4));
    }
    // V write addresses (waves 0-3 only; tid<256 there)
    const int cv = tid & 15, vd0 = ((tid >> 4) & 15) << 2;
    int vwa[4];
    #pragma unroll
    for (int j = 0; j < 4; ++j) {
        const int row = vd0 + j;
        vwa[j] = 16384 + row * 128 + ((cv << 3) ^ ((row & 7) << 4));
    }
    // K staging geometry (linear dest + pre-swizzled source), waves 0-3
    int kdst[2];
    const unsigned short* kg[2];
    {
        const unsigned short* kbase =
            k + (size_t)(b * SEQ + half * (SEQ / 2)) * D_MODEL + h * DK;
        #pragma unroll
        for (int r = 0; r < 2; ++r) {
            int phys = ((w & 3) + 4 * r) * 1024 + lane * 16;
            int row  = phys >> 7;
            int slot = (phys >> 4) & 7;
            kdst[r]  = ((w & 3) + 4 * r) * 1024;
            kg[r]    = kbase + (size_t)row * D_MODEL + (slot ^ (row & 7)) * 8;
        }
    }
    const unsigned short* vg =
        v + (size_t)(b * SEQ + half * (SEQ / 2) + cv) * D_MODEL + h * DK + vd0;
    const int TS = 64 * D_MODEL;   // tile stride (elements)

    us4 va, vb_, vc, vd;   // V in-flight regs (waves 0-3)

    // ---- prologue: tile 0 ----
    if (w < 4) {
        gload_lds16(kg[0], sm + kdst[0]);
        gload_lds16(kg[1], sm + kdst[1]);
        va  = *(const us4*)(vg);
        vb_ = *(const us4*)(vg + 16 * D_MODEL);
        vc  = *(const us4*)(vg + 32 * D_MODEL);
        vd  = *(const us4*)(vg + 48 * D_MODEL);
        #pragma unroll
        for (int j = 0; j < 4; ++j) {
            uint2 pk;
            pk.x = (unsigned)va[j] | ((unsigned)vb_[j] << 16);
            pk.y = (unsigned)vc[j] | ((unsigned)vd[j] << 16);
            *(uint2*)(sm + vwa[j]) = pk;
        }
    }
    kg[0] += TS; kg[1] += TS; vg += TS;
    barrier_lgkm();

    for (int kt = 0; kt < NT2; kt += 2) {
        #pragma unroll
        for (int u = 0; u < 2; ++u) {
            // ---- prefetch tile kt+u+1 (tail overrun stays inside d_ws) ----
            if (w < 4) {
                gload_lds16(kg[0], sm + (u ^ 1) * 8192 + kdst[0]);
                gload_lds16(kg[1], sm + (u ^ 1) * 8192 + kdst[1]);
                va  = *(const us4*)(vg);
                vb_ = *(const us4*)(vg + 16 * D_MODEL);
                vc  = *(const us4*)(vg + 32 * D_MODEL);
                vd  = *(const us4*)(vg + 48 * D_MODEL);
            }
            kg[0] += TS; kg[1] += TS; vg += TS;
            __builtin_amdgcn_sched_barrier(0);

            // ---- S = Q @ K^T ----
            f32x4 sacc[4] = {f32x4{0,0,0,0}, f32x4{0,0,0,0},
                             f32x4{0,0,0,0}, f32x4{0,0,0,0}};
            __builtin_amdgcn_s_setprio(1);
            #pragma unroll
            for (int kstep = 0; kstep < 2; ++kstep) {
                short8 af = kstep ? qf1 : qf0;
                #pragma unroll
                for (int ks = 0; ks < 4; ++ks) {
                    short8 bf = *(const short8*)(sm + u * 8192 + ks * 2048 +
                                                 (kstep ? rb1 : rb0));
                    sacc[ks] = __builtin_amdgcn_mfma_f32_16x16x32_bf16(
                                   af, bf, sacc[ks], 0, 0, 0);
                }
            }
            __builtin_amdgcn_s_setprio(0);

            // ---- defer-max check: lane-local, zero cross-lane ops ----
            float rm[4], dm;
            #pragma unroll
            for (int reg = 0; reg < 4; ++reg)
                rm[reg] = fmaxf(fmaxf(sacc[0][reg], sacc[1][reg]),
                                fmaxf(sacc[2][reg], sacc[3][reg]));
            dm = fmaxf(fmaxf(rm[0] - m_run[0], rm[1] - m_run[1]),
                       fmaxf(rm[2] - m_run[2], rm[3] - m_run[3]));
            if (__any(dm > 11.0f)) {   // rare slow path: full row-max + rescale
                #pragma unroll
                for (int reg = 0; reg < 4; ++reg) {
                    float mx = rm[reg];
                    mx = fmaxf(mx, __shfl_xor(mx, 1));
                    mx = fmaxf(mx, __shfl_xor(mx, 2));
                    mx = fmaxf(mx, __shfl_xor(mx, 4));
                    mx = fmaxf(mx, __shfl_xor(mx, 8));
                    const float mnew = fmaxf(m_run[reg], mx);
                    const float sc = fast_exp2(m_run[reg] - mnew);
                    m_run[reg] = mnew;
                    lacc[reg] *= sc;
                    o[0][reg] *= sc;
                    o[1][reg] *= sc;
                    o[2][reg] *= sc;
                    o[3][reg] *= sc;
                }
            }
            #pragma unroll
            for (int reg = 0; reg < 4; ++reg) {
                const float m = m_run[reg];
                float p0 = fast_exp2(sacc[0][reg] - m);
                float p1 = fast_exp2(sacc[1][reg] - m);
                float p2 = fast_exp2(sacc[2][reg] - m);
                float p3 = fast_exp2(sacc[3][reg] - m);
                uint2 pw;
                pw.x = f2bf2(p0, p1);   // pi-positions 4c, 4c+1
                pw.y = f2bf2(p2, p3);   // pi-positions 4c+2, 4c+3
                *(uint2*)(sm + pwa[reg]) = pw;
            }

            // ---- O += P @ V ; l += P @ ones ----
            __builtin_amdgcn_s_setprio(1);
            #pragma unroll
            for (int kstep = 0; kstep < 2; ++kstep) {
                short8 paf = *(const short8*)(sm + (kstep ? bp1 : bp0));
                lacc = __builtin_amdgcn_mfma_f32_16x16x32_bf16(paf, ONES, lacc, 0, 0, 0);
                #pragma unroll
                for (int dsub = 0; dsub < 4; ++dsub) {
                    short8 vbf = *(const short8*)(sm + 16384 + u * 8192 +
                                                  dsub * 2048 + (kstep ? rb1 : rb0));
                    o[dsub] = __builtin_amdgcn_mfma_f32_16x16x32_bf16(
                                  paf, vbf, o[dsub], 0, 0, 0);
                }
            }
            __builtin_amdgcn_s_setprio(0);

            // ---- V(next) regs -> LDS (reg-dep retires this tile's prefetch) ----
            if (w < 4) {
                #pragma unroll
                for (int j = 0; j < 4; ++j) {
                    uint2 pk;
                    pk.x = (unsigned)va[j] | ((unsigned)vb_[j] << 16);
                    pk.y = (unsigned)vc[j] | ((unsigned)vd[j] << 16);
                    *(uint2*)(sm + (u ^ 1) * 8192 + vwa[j]) = pk;
                }
            }
            barrier_lgkm();
        }
    }

    // ---- store partial: o (bf16, unnormalized) + (m, l) f32 per row ----
    const size_t obase = (size_t)half * ((size_t)MTOT * D_MODEL) +
                         (size_t)(b * SEQ) * D_MODEL + h * DK;
    #pragma unroll
    for (int reg = 0; reg < 4; ++reg) {
        const int qrow = q0 + (w << 4) + (g << 2) + reg;
        unsigned short* ob = opart + obase + (size_t)qrow * D_MODEL;
        #pragma unroll
        for (int dsub = 0; dsub < 4; ++dsub)
            ob[dsub * 16 + c] = f2bf1(o[dsub][reg]);
        if (c == 0) {
            float2 mlv;
            mlv.x = m_run[reg];
            mlv.y = lacc[reg];
            ((float2*)mlpart)[(size_t)half * MTOT * HEADS +
                              (size_t)(b * SEQ + qrow) * HEADS + h] = mlv;
        }
    }
}

// ---------------- combine: merge the two KV-halves exactly ------------------
__global__ __launch_bounds__(256) void combine_k(
    const unsigned short* __restrict__ op, const float* __restrict__ mlpart,
    unsigned short* __restrict__ cb)
{
    const int t   = blockIdx.x * 256 + threadIdx.x;   // < MTOT*768/8
    const int row = t / 96;
    const int gi  = t - row * 96;
    const int col = gi << 3;
    const int h   = gi >> 3;

    const float2* mlp = (const float2*)mlpart;
    const float2 ml0 = mlp[(size_t)row * HEADS + h];
    const float2 ml1 = mlp[(size_t)MTOT * HEADS + (size_t)row * HEADS + h];
    const float m  = fmaxf(ml0.x, ml1.x);
    const float s0 = fast_exp2(ml0.x - m);
    const float s1 = fast_exp2(ml1.x - m);
    const float inv = 1.0f / (ml0.y * s0 + ml1.y * s1);
    const float a0 = s0 * inv, a1 = s1 * inv;

    const size_t off = (size_t)row * D_MODEL + col;
    us4 x0  = *(const us4*)(op + off);
    us4 x0b = *(const us4*)(op + off + 4);
    us4 x1  = *(const us4*)(op + (size_t)MTOT * D_MODEL + off);
    us4 x1b = *(const us4*)(op + (size_t)MTOT * D_MODEL + off + 4);

    union { unsigned short u[8]; short8 s; } r;
    #pragma unroll
    for (int j = 0; j < 4; ++j) {
        r.u[j]     = f2bf1(bf2f(x0[j])  * a0 + bf2f(x1[j])  * a1);
        r.u[4 + j] = f2bf1(bf2f(x0b[j]) * a0 + bf2f(x1b[j]) * a1);
    }
    *(short8*)(cb + off) = r.s;
}

// ---------------------------------------------------------------------------
extern "C" void kernel_launch(void* const* d_in, const int* in_sizes, int n_in,
                              void* d_out, int out_size, void* d_ws, size_t ws_size,
                              hipStream_t stream) {
    const float* query = (const float*)d_in[0];
    const float* key   = (const float*)d_in[1];
    const float* value = (const float*)d_in[2];
    const float* Wq = (const float*)d_in[3];
    const float* bq = (const float*)d_in[4];
    const float* Wk = (const float*)d_in[5];
    const float* bk = (const float*)d_in[6];
    const float* Wv = (const float*)d_in[7];
    const float* bv = (const float*)d_in[8];
    const float* Wo = (const float*)d_in[9];
    const float* bo = (const float*)d_in[10];
    float* out = (float*)d_out;

    const size_t mat = (size_t)MTOT * D_MODEL;      // 3.145M elems
    unsigned short* qb  = (unsigned short*)d_ws;    // projected Q/K/V (bf16)
    unsigned short* kb  = qb + mat;
    unsigned short* vb  = kb + mat;
    unsigned short* cb  = vb + mat;                 // combined context (bf16)
    unsigned short* Wqt = cb + mat;                 // transposed bf16 weights
    unsigned short* Wkt = Wqt + (size_t)D_MODEL * D_MODEL;
    unsigned short* Wvt = Wkt + (size_t)D_MODEL * D_MODEL;
    unsigned short* Wot = Wvt + (size_t)D_MODEL * D_MODEL;
    unsigned short* op  = Wot + (size_t)D_MODEL * D_MODEL;   // o partials, 2 halves
    float*          mlp = (float*)(op + 2 * mat);            // (m,l) partials

    cvt_wt_k<<<dim3(D_MODEL / 32, D_MODEL / 32, 4), 256, 0, stream>>>(
        Wq, Wk, Wv, Wo, Wqt, Wkt, Wvt, Wot);

    gemm_qkv_k<<<dim3(576), 256, 0, stream>>>(
        query, key, value, Wqt, Wkt, Wvt, bq, bk, bv, qb, kb, vb);

    attn_mfma_k<<<dim3(768), 512, 0, stream>>>(qb, kb, vb, op, mlp);

    combine_k<<<dim3(MTOT * D_MODEL / 8 / 256), 256, 0, stream>>>(op, mlp, cb);

    gemm_o_k<<<dim3(192), 256, 0, stream>>>(cb, Wot, bo, out);
}

// Round 9
// 113.379 us; speedup vs baseline: 1.2214x; 1.2214x over previous
//
#include <hip/hip_runtime.h>
#include <hip/hip_bf16.h>
#include <math.h>

#define D_MODEL 768
#define HEADS 12
#define DK 64
#define SEQ 2048
#define BATCH 2
#define MTOT (BATCH * SEQ)   // 4096
#define QSCALE 0.18033688011112042f   // 0.125 * log2(e): softmax in exp2 domain

using short8 = __attribute__((ext_vector_type(8))) short;
using us4    = __attribute__((ext_vector_type(4))) unsigned short;
using f32x4  = __attribute__((ext_vector_type(4))) float;

// ---------------- helpers ---------------------------------------------------
static __device__ __forceinline__ unsigned f2bf2(float x, float y) {
    __hip_bfloat162 t = __float22bfloat162_rn(float2{x, y});
    return *reinterpret_cast<unsigned*>(&t);
}
static __device__ __forceinline__ unsigned short f2bf1(float x) {
    __hip_bfloat16 t = __float2bfloat16(x);
    return *reinterpret_cast<unsigned short*>(&t);
}
static __device__ __forceinline__ float bf2f(unsigned short u) {
    unsigned v = (unsigned)u << 16;
    return __uint_as_float(v);
}
static __device__ __forceinline__ short8 cvt8(float4 a, float4 b) {
    union { unsigned u[4]; short8 s; } r;
    r.u[0] = f2bf2(a.x, a.y);
    r.u[1] = f2bf2(a.z, a.w);
    r.u[2] = f2bf2(b.x, b.y);
    r.u[3] = f2bf2(b.z, b.w);
    return r.s;
}
static __device__ __forceinline__ float fast_exp2(float x) {
#if __has_builtin(__builtin_amdgcn_exp2f)
    return __builtin_amdgcn_exp2f(x);
#else
    return __expf(x * 0.6931471805599453f);
#endif
}

static __device__ __forceinline__ void gload_lds16(const void* g, void* l) {
    __builtin_amdgcn_global_load_lds(
        (const __attribute__((address_space(1))) void*)g,
        (__attribute__((address_space(3))) void*)l, 16, 0, 0);
}

// barrier draining LDS ops only (VMEM prefetch stays in flight unless a
// register dependency already retired it)
static __device__ __forceinline__ void barrier_lgkm() {
    asm volatile("s_waitcnt lgkmcnt(0)" ::: "memory");
    __builtin_amdgcn_s_barrier();
    __builtin_amdgcn_sched_barrier(0);
}
static __device__ __forceinline__ void barrier_vm0() {
    asm volatile("s_waitcnt vmcnt(0)" ::: "memory");
    __builtin_amdgcn_s_barrier();
    __builtin_amdgcn_sched_barrier(0);
}

// ---------------- pre-pass: W[k][n] fp32 -> Wt[n][k] bf16 (4 W's fused) -----
__global__ __launch_bounds__(256) void cvt_wt_k(
    const float* __restrict__ Wq, const float* __restrict__ Wk,
    const float* __restrict__ Wv, const float* __restrict__ Wo,
    unsigned short* __restrict__ Wqt, unsigned short* __restrict__ Wkt,
    unsigned short* __restrict__ Wvt, unsigned short* __restrict__ Wot)
{
    const int z = blockIdx.z;
    const float* W = z == 0 ? Wq : z == 1 ? Wk : z == 2 ? Wv : Wo;
    unsigned short* Wt = z == 0 ? Wqt : z == 1 ? Wkt : z == 2 ? Wvt : Wot;
    __shared__ float t[32][33];
    const int n0 = blockIdx.x * 32, k0 = blockIdx.y * 32;
    const int tx = threadIdx.x & 31;
    const int ty0 = (threadIdx.x >> 5) * 4;
    #pragma unroll
    for (int j = 0; j < 4; ++j)
        t[ty0 + j][tx] = W[(size_t)(k0 + ty0 + j) * D_MODEL + n0 + tx];
    __syncthreads();
    #pragma unroll
    for (int j = 0; j < 4; ++j)
        Wt[(size_t)(n0 + ty0 + j) * D_MODEL + k0 + tx] = f2bf1(t[tx][ty0 + j]);
}

// ---- QKV GEMM: 128x128 tile, BK=64, 512 thr (8 waves 2x4), 2 bufs ----------
// A fp32 reg-staged -> bf16 LDS (write-late, counted waits); B via gload_lds.
// LDS 64KB: A: 0+buf*16384 ; B: 32768+buf*16384. 2 blocks/CU -> 16 waves/CU.
__global__ __launch_bounds__(512) void gemm_qkv_k(
    const float* __restrict__ query, const float* __restrict__ key,
    const float* __restrict__ value,
    const unsigned short* __restrict__ Wqt, const unsigned short* __restrict__ Wkt,
    const unsigned short* __restrict__ Wvt,
    const float* __restrict__ bq, const float* __restrict__ bk,
    const float* __restrict__ bv,
    unsigned short* __restrict__ qb, unsigned short* __restrict__ kb,
    unsigned short* __restrict__ vb)
{
    __shared__ __align__(16) char gsm[65536];

    const int bid = blockIdx.x;
    const int xcd = bid & 7;
    const int idx = bid >> 3;          // 0..71
    const int z   = idx / 24;
    const int rr  = idx % 24;
    const int brow = (xcd * 4 + rr / 6) * 128;
    const int bcol = (rr % 6) * 128;

    const float* A           = z == 0 ? query : z == 1 ? key : value;
    const unsigned short* Wt = z == 0 ? Wqt : z == 1 ? Wkt : Wvt;
    const float* bias        = z == 0 ? bq  : z == 1 ? bk  : bv;
    unsigned short* C        = z == 0 ? qb  : z == 1 ? kb  : vb;
    const float scale        = z == 0 ? QSCALE : 1.0f;

    const int tid  = threadIdx.x;
    const int w    = tid >> 6;
    const int lane = tid & 63;
    const int g    = lane >> 4, c = lane & 15;
    const int wr   = w >> 2, wc = w & 3;   // 2x4 wave grid

    f32x4 acc[4][2] = {};

    // hoisted read bases (row&7 == c&7 for every fragment row)
    const int xc  = (c & 7) << 4;
    const int rb0 = c * 128 + ((g * 16) ^ xc);
    const int rb1 = c * 128 + ((64 + g * 16) ^ xc);

    // B staging: 16KB = 16 chunks of 1KB; 2 chunks per wave
    int bsrow[2], bsoff[2], bsdst[2];
    #pragma unroll
    for (int r = 0; r < 2; ++r) {
        int phys = (w * 2 + r) * 1024 + lane * 16;
        int row  = phys >> 7;
        int slot = (phys >> 4) & 7;
        bsrow[r] = row;
        bsoff[r] = (slot ^ (row & 7)) * 8;
        bsdst[r] = (w * 2 + r) * 1024;
    }
    // fp32-A staging: thread owns row ar, 16 k-elems at ac
    const int ar = tid >> 2;
    const int ac = (tid & 3) << 4;
    int awa[2];
    #pragma unroll
    for (int i = 0; i < 2; ++i)
        awa[i] = ar * 128 + (((ac << 1) + 16 * i) ^ ((ar & 7) << 4));
    const float* Ap32 = A + (size_t)(brow + ar) * D_MODEL + ac;

    float4 ra0, ra1, ra2, ra3;   // fp32 A in-flight regs

    auto stageB = [&](int k0, int buf) {
        #pragma unroll
        for (int r = 0; r < 2; ++r)
            gload_lds16(Wt + (size_t)(bcol + bsrow[r]) * D_MODEL + k0 + bsoff[r],
                        gsm + 32768 + buf * 16384 + bsdst[r]);
    };
    auto loadA32 = [&](int k0) {
        ra0 = *(const float4*)(Ap32 + k0);
        ra1 = *(const float4*)(Ap32 + k0 + 4);
        ra2 = *(const float4*)(Ap32 + k0 + 8);
        ra3 = *(const float4*)(Ap32 + k0 + 12);
    };
    auto writeA32 = [&](int buf) {   // reg-dep vmcnt wait retires same-step stageB
        *(short8*)(gsm + buf * 16384 + awa[0]) = cvt8(ra0, ra1);
        *(short8*)(gsm + buf * 16384 + awa[1]) = cvt8(ra2, ra3);
    };

    // prologue
    stageB(0, 0);
    loadA32(0);
    writeA32(0);
    barrier_lgkm();

    for (int k0 = 0; k0 < D_MODEL; k0 += 128) {
        #pragma unroll
        for (int u = 0; u < 2; ++u) {
            const int kn = min(k0 + u * 64 + 64, D_MODEL - 64);   // tail dup ok
            stageB(kn, u ^ 1);
            loadA32(kn);
            __builtin_amdgcn_sched_barrier(0);

            __builtin_amdgcn_s_setprio(1);
            #pragma unroll
            for (int kstep = 0; kstep < 2; ++kstep) {
                const int rb = kstep ? rb1 : rb0;
                short8 af[4], bf[2];
                #pragma unroll
                for (int m = 0; m < 4; ++m)
                    af[m] = *(const short8*)(gsm + u * 16384 + wr * 8192 +
                                             m * 2048 + rb);
                #pragma unroll
                for (int n = 0; n < 2; ++n)
                    bf[n] = *(const short8*)(gsm + 32768 + u * 16384 +
                                             wc * 4096 + n * 2048 + rb);
                #pragma unroll
                for (int m = 0; m < 4; ++m)
                    #pragma unroll
                    for (int n = 0; n < 2; ++n)
                        acc[m][n] = __builtin_amdgcn_mfma_f32_16x16x32_bf16(
                                        af[m], bf[n], acc[m][n], 0, 0, 0);
            }
            __builtin_amdgcn_s_setprio(0);

            writeA32(u ^ 1);
            barrier_lgkm();
        }
    }

    #pragma unroll
    for (int m = 0; m < 4; ++m)
        #pragma unroll
        for (int n = 0; n < 2; ++n) {
            const int col = bcol + wc * 32 + n * 16 + c;
            const float bval = bias[col];
            #pragma unroll
            for (int j = 0; j < 4; ++j) {
                const int row = brow + wr * 64 + m * 16 + g * 4 + j;
                C[(size_t)row * D_MODEL + col] = f2bf1((acc[m][n][j] + bval) * scale);
            }
        }
}

// ---- O GEMM: 64x64 tile, BK=64, 256 thr (2x2 waves), 2 bufs (R7 proven) ----
__global__ __launch_bounds__(256) void gemm_o_k(
    const unsigned short* __restrict__ A, const unsigned short* __restrict__ Wt,
    const float* __restrict__ bias, float* __restrict__ C)
{
    __shared__ __align__(16) char gsm[32768];   // A: 0+buf*8192 ; B: 16384+buf*8192

    const int bid = blockIdx.x;
    const int xcd = bid & 7;
    const int idx = bid >> 3;          // 0..95
    const int brow = (xcd * 8 + idx / 12) * 64;
    const int bcol = (idx % 12) * 64;

    const int tid  = threadIdx.x;
    const int w    = tid >> 6;
    const int lane = tid & 63;
    const int g    = lane >> 4, c = lane & 15;
    const int wr   = w >> 1, wc = w & 1;

    f32x4 acc[2][2] = {{f32x4{0,0,0,0}, f32x4{0,0,0,0}},
                       {f32x4{0,0,0,0}, f32x4{0,0,0,0}}};

    const int xc  = (c & 7) << 4;
    const int rb0 = c * 128 + ((g * 16) ^ xc);
    const int rb1 = c * 128 + ((64 + g * 16) ^ xc);
    const int a0 = rb0 + wr * 4096, a1 = rb1 + wr * 4096;
    const int b0r = rb0 + 16384 + wc * 4096, b1r = rb1 + 16384 + wc * 4096;

    int bsrow[2], bsoff[2], bsdst[2];
    #pragma unroll
    for (int r = 0; r < 2; ++r) {
        int phys = (w + 4 * r) * 1024 + lane * 16;
        int row  = phys >> 7;
        int slot = (phys >> 4) & 7;
        bsrow[r] = row;
        bsoff[r] = (slot ^ (row & 7)) * 8;
        bsdst[r] = (w + 4 * r) * 1024;
    }

    auto stage = [&](int k0, int buf) {
        #pragma unroll
        for (int r = 0; r < 2; ++r) {
            gload_lds16(A  + (size_t)(brow + bsrow[r]) * D_MODEL + k0 + bsoff[r],
                        gsm + buf * 8192 + bsdst[r]);
            gload_lds16(Wt + (size_t)(bcol + bsrow[r]) * D_MODEL + k0 + bsoff[r],
                        gsm + 16384 + buf * 8192 + bsdst[r]);
        }
    };

    stage(0, 0);
    barrier_vm0();

    for (int k0 = 0; k0 < D_MODEL; k0 += 128) {
        #pragma unroll
        for (int u = 0; u < 2; ++u) {
            const int kn = min(k0 + u * 64 + 64, D_MODEL - 64);
            stage(kn, u ^ 1);
            __builtin_amdgcn_sched_barrier(0);

            #pragma unroll
            for (int kstep = 0; kstep < 2; ++kstep) {
                short8 af[2], bf[2];
                #pragma unroll
                for (int m = 0; m < 2; ++m)
                    af[m] = *(const short8*)(gsm + u * 8192 + m * 2048 +
                                             (kstep ? a1 : a0));
                #pragma unroll
                for (int n = 0; n < 2; ++n)
                    bf[n] = *(const short8*)(gsm + u * 8192 + n * 2048 +
                                             (kstep ? b1r : b0r));
                #pragma unroll
                for (int m = 0; m < 2; ++m)
                    #pragma unroll
                    for (int n = 0; n < 2; ++n)
                        acc[m][n] = __builtin_amdgcn_mfma_f32_16x16x32_bf16(
                                        af[m], bf[n], acc[m][n], 0, 0, 0);
            }
            barrier_vm0();
        }
    }

    #pragma unroll
    for (int m = 0; m < 2; ++m)
        #pragma unroll
        for (int n = 0; n < 2; ++n) {
            const int col = bcol + wc * 32 + n * 16 + c;
            const float bval = bias[col];
            #pragma unroll
            for (int j = 0; j < 4; ++j) {
                const int row = brow + wr * 32 + m * 16 + g * 4 + j;
                C[(size_t)row * D_MODEL + col] = acc[m][n][j] + bval;
            }
        }
}

// ---------------- Flash attention: KV-split x2, 8 waves, 2 bufs -------------
// (unchanged from R8 — measured-good)
__global__ __launch_bounds__(512) void attn_mfma_k(
    const unsigned short* __restrict__ q, const unsigned short* __restrict__ k,
    const unsigned short* __restrict__ v, unsigned short* __restrict__ opart,
    float* __restrict__ mlpart)
{
    __shared__ __align__(16) char sm[49152];

    const int tid  = threadIdx.x;
    const int w    = tid >> 6;
    const int lane = tid & 63;
    const int g    = lane >> 4;
    const int c    = lane & 15;

    const int bid  = blockIdx.x;
    const int swz  = (bid & 7) * 96 + (bid >> 3);
    const int qt   = swz & 15;
    const int rest = swz >> 4;
    const int half = rest & 1;
    const int hb   = rest >> 1;
    const int h    = hb % HEADS;
    const int b    = hb / HEADS;
    const int q0   = qt * 128;
    const int NT2  = 16;

    short8 qf0, qf1;
    {
        const int qrow = q0 + (w << 4) + c;
        const unsigned short* qp = q + (size_t)(b * SEQ + qrow) * D_MODEL + h * DK;
        qf0 = *(const short8*)(qp + g * 8);
        qf1 = *(const short8*)(qp + 32 + g * 8);
    }

    float m_run[4] = {-INFINITY, -INFINITY, -INFINITY, -INFINITY};
    f32x4 lacc = f32x4{0, 0, 0, 0};
    f32x4 o[4] = {f32x4{0,0,0,0}, f32x4{0,0,0,0}, f32x4{0,0,0,0}, f32x4{0,0,0,0}};
    const short8 ONES = {0x3F80, 0x3F80, 0x3F80, 0x3F80,
                         0x3F80, 0x3F80, 0x3F80, 0x3F80};

    const int xc  = (c & 7) << 4;
    const int rb0 = c * 128 + ((g * 16) ^ xc);
    const int rb1 = c * 128 + ((64 + g * 16) ^ xc);
    const int bp0 = 32768 + w * 2048 + rb0;
    const int bp1 = 32768 + w * 2048 + rb1;

    int pwa[4];
    #pragma unroll
    for (int r = 0; r < 4; ++r) {
        const int row = (g << 2) + r;
        pwa[r] = 32768 + w * 2048 + row * 128 + ((c << 3) ^ ((row & 7) << 4));
    }
    const int cv = tid & 15, vd0 = ((tid >> 4) & 15) << 2;
    int vwa[4];
    #pragma unroll
    for (int j = 0; j < 4; ++j) {
        const int row = vd0 + j;
        vwa[j] = 16384 + row * 128 + ((cv << 3) ^ ((row & 7) << 4));
    }
    int kdst[2];
    const unsigned short* kg[2];
    {
        const unsigned short* kbase =
            k + (size_t)(b * SEQ + half * (SEQ / 2)) * D_MODEL + h * DK;
        #pragma unroll
        for (int r = 0; r < 2; ++r) {
            int phys = ((w & 3) + 4 * r) * 1024 + lane * 16;
            int row  = phys >> 7;
            int slot = (phys >> 4) & 7;
            kdst[r]  = ((w & 3) + 4 * r) * 1024;
            kg[r]    = kbase + (size_t)row * D_MODEL + (slot ^ (row & 7)) * 8;
        }
    }
    const unsigned short* vg =
        v + (size_t)(b * SEQ + half * (SEQ / 2) + cv) * D_MODEL + h * DK + vd0;
    const int TS = 64 * D_MODEL;

    us4 va, vb_, vc, vd;

    if (w < 4) {
        gload_lds16(kg[0], sm + kdst[0]);
        gload_lds16(kg[1], sm + kdst[1]);
        va  = *(const us4*)(vg);
        vb_ = *(const us4*)(vg + 16 * D_MODEL);
        vc  = *(const us4*)(vg + 32 * D_MODEL);
        vd  = *(const us4*)(vg + 48 * D_MODEL);
        #pragma unroll
        for (int j = 0; j < 4; ++j) {
            uint2 pk;
            pk.x = (unsigned)va[j] | ((unsigned)vb_[j] << 16);
            pk.y = (unsigned)vc[j] | ((unsigned)vd[j] << 16);
            *(uint2*)(sm + vwa[j]) = pk;
        }
    }
    kg[0] += TS; kg[1] += TS; vg += TS;
    barrier_lgkm();

    for (int kt = 0; kt < NT2; kt += 2) {
        #pragma unroll
        for (int u = 0; u < 2; ++u) {
            if (w < 4) {
                gload_lds16(kg[0], sm + (u ^ 1) * 8192 + kdst[0]);
                gload_lds16(kg[1], sm + (u ^ 1) * 8192 + kdst[1]);
                va  = *(const us4*)(vg);
                vb_ = *(const us4*)(vg + 16 * D_MODEL);
                vc  = *(const us4*)(vg + 32 * D_MODEL);
                vd  = *(const us4*)(vg + 48 * D_MODEL);
            }
            kg[0] += TS; kg[1] += TS; vg += TS;
            __builtin_amdgcn_sched_barrier(0);

            f32x4 sacc[4] = {f32x4{0,0,0,0}, f32x4{0,0,0,0},
                             f32x4{0,0,0,0}, f32x4{0,0,0,0}};
            __builtin_amdgcn_s_setprio(1);
            #pragma unroll
            for (int kstep = 0; kstep < 2; ++kstep) {
                short8 af = kstep ? qf1 : qf0;
                #pragma unroll
                for (int ks = 0; ks < 4; ++ks) {
                    short8 bf = *(const short8*)(sm + u * 8192 + ks * 2048 +
                                                 (kstep ? rb1 : rb0));
                    sacc[ks] = __builtin_amdgcn_mfma_f32_16x16x32_bf16(
                                   af, bf, sacc[ks], 0, 0, 0);
                }
            }
            __builtin_amdgcn_s_setprio(0);

            float rm[4], dm;
            #pragma unroll
            for (int reg = 0; reg < 4; ++reg)
                rm[reg] = fmaxf(fmaxf(sacc[0][reg], sacc[1][reg]),
                                fmaxf(sacc[2][reg], sacc[3][reg]));
            dm = fmaxf(fmaxf(rm[0] - m_run[0], rm[1] - m_run[1]),
                       fmaxf(rm[2] - m_run[2], rm[3] - m_run[3]));
            if (__any(dm > 11.0f)) {
                #pragma unroll
                for (int reg = 0; reg < 4; ++reg) {
                    float mx = rm[reg];
                    mx = fmaxf(mx, __shfl_xor(mx, 1));
                    mx = fmaxf(mx, __shfl_xor(mx, 2));
                    mx = fmaxf(mx, __shfl_xor(mx, 4));
                    mx = fmaxf(mx, __shfl_xor(mx, 8));
                    const float mnew = fmaxf(m_run[reg], mx);
                    const float sc = fast_exp2(m_run[reg] - mnew);
                    m_run[reg] = mnew;
                    lacc[reg] *= sc;
                    o[0][reg] *= sc;
                    o[1][reg] *= sc;
                    o[2][reg] *= sc;
                    o[3][reg] *= sc;
                }
            }
            #pragma unroll
            for (int reg = 0; reg < 4; ++reg) {
                const float m = m_run[reg];
                float p0 = fast_exp2(sacc[0][reg] - m);
                float p1 = fast_exp2(sacc[1][reg] - m);
                float p2 = fast_exp2(sacc[2][reg] - m);
                float p3 = fast_exp2(sacc[3][reg] - m);
                uint2 pw;
                pw.x = f2bf2(p0, p1);
                pw.y = f2bf2(p2, p3);
                *(uint2*)(sm + pwa[reg]) = pw;
            }

            __builtin_amdgcn_s_setprio(1);
            #pragma unroll
            for (int kstep = 0; kstep < 2; ++kstep) {
                short8 paf = *(const short8*)(sm + (kstep ? bp1 : bp0));
                lacc = __builtin_amdgcn_mfma_f32_16x16x32_bf16(paf, ONES, lacc, 0, 0, 0);
                #pragma unroll
                for (int dsub = 0; dsub < 4; ++dsub) {
                    short8 vbf = *(const short8*)(sm + 16384 + u * 8192 +
                                                  dsub * 2048 + (kstep ? rb1 : rb0));
                    o[dsub] = __builtin_amdgcn_mfma_f32_16x16x32_bf16(
                                  paf, vbf, o[dsub], 0, 0, 0);
                }
            }
            __builtin_amdgcn_s_setprio(0);

            if (w < 4) {
                #pragma unroll
                for (int j = 0; j < 4; ++j) {
                    uint2 pk;
                    pk.x = (unsigned)va[j] | ((unsigned)vb_[j] << 16);
                    pk.y = (unsigned)vc[j] | ((unsigned)vd[j] << 16);
                    *(uint2*)(sm + (u ^ 1) * 8192 + vwa[j]) = pk;
                }
            }
            barrier_lgkm();
        }
    }

    const size_t obase = (size_t)half * ((size_t)MTOT * D_MODEL) +
                         (size_t)(b * SEQ) * D_MODEL + h * DK;
    #pragma unroll
    for (int reg = 0; reg < 4; ++reg) {
        const int qrow = q0 + (w << 4) + (g << 2) + reg;
        unsigned short* ob = opart + obase + (size_t)qrow * D_MODEL;
        #pragma unroll
        for (int dsub = 0; dsub < 4; ++dsub)
            ob[dsub * 16 + c] = f2bf1(o[dsub][reg]);
        if (c == 0) {
            float2 mlv;
            mlv.x = m_run[reg];
            mlv.y = lacc[reg];
            ((float2*)mlpart)[(size_t)half * MTOT * HEADS +
                              (size_t)(b * SEQ + qrow) * HEADS + h] = mlv;
        }
    }
}

// ---------------- combine: merge the two KV-halves exactly ------------------
__global__ __launch_bounds__(256) void combine_k(
    const unsigned short* __restrict__ op, const float* __restrict__ mlpart,
    unsigned short* __restrict__ cb)
{
    const int t   = blockIdx.x * 256 + threadIdx.x;
    const int row = t / 96;
    const int gi  = t - row * 96;
    const int col = gi << 3;
    const int h   = gi >> 3;

    const float2* mlp = (const float2*)mlpart;
    const float2 ml0 = mlp[(size_t)row * HEADS + h];
    const float2 ml1 = mlp[(size_t)MTOT * HEADS + (size_t)row * HEADS + h];
    const float m  = fmaxf(ml0.x, ml1.x);
    const float s0 = fast_exp2(ml0.x - m);
    const float s1 = fast_exp2(ml1.x - m);
    const float inv = 1.0f / (ml0.y * s0 + ml1.y * s1);
    const float a0 = s0 * inv, a1 = s1 * inv;

    const size_t off = (size_t)row * D_MODEL + col;
    us4 x0  = *(const us4*)(op + off);
    us4 x0b = *(const us4*)(op + off + 4);
    us4 x1  = *(const us4*)(op + (size_t)MTOT * D_MODEL + off);
    us4 x1b = *(const us4*)(op + (size_t)MTOT * D_MODEL + off + 4);

    union { unsigned short u[8]; short8 s; } r;
    #pragma unroll
    for (int j = 0; j < 4; ++j) {
        r.u[j]     = f2bf1(bf2f(x0[j])  * a0 + bf2f(x1[j])  * a1);
        r.u[4 + j] = f2bf1(bf2f(x0b[j]) * a0 + bf2f(x1b[j]) * a1);
    }
    *(short8*)(cb + off) = r.s;
}

// ---------------------------------------------------------------------------
extern "C" void kernel_launch(void* const* d_in, const int* in_sizes, int n_in,
                              void* d_out, int out_size, void* d_ws, size_t ws_size,
                              hipStream_t stream) {
    const float* query = (const float*)d_in[0];
    const float* key   = (const float*)d_in[1];
    const float* value = (const float*)d_in[2];
    const float* Wq = (const float*)d_in[3];
    const float* bq = (const float*)d_in[4];
    const float* Wk = (const float*)d_in[5];
    const float* bk = (const float*)d_in[6];
    const float* Wv = (const float*)d_in[7];
    const float* bv = (const float*)d_in[8];
    const float* Wo = (const float*)d_in[9];
    const float* bo = (const float*)d_in[10];
    float* out = (float*)d_out;

    const size_t mat = (size_t)MTOT * D_MODEL;      // 3.145M elems
    unsigned short* qb  = (unsigned short*)d_ws;    // projected Q/K/V (bf16)
    unsigned short* kb  = qb + mat;
    unsigned short* vb  = kb + mat;
    unsigned short* cb  = vb + mat;                 // combined context (bf16)
    unsigned short* Wqt = cb + mat;                 // transposed bf16 weights
    unsigned short* Wkt = Wqt + (size_t)D_MODEL * D_MODEL;
    unsigned short* Wvt = Wkt + (size_t)D_MODEL * D_MODEL;
    unsigned short* Wot = Wvt + (size_t)D_MODEL * D_MODEL;
    unsigned short* op  = Wot + (size_t)D_MODEL * D_MODEL;   // o partials, 2 halves
    float*          mlp = (float*)(op + 2 * mat);            // (m,l) partials

    cvt_wt_k<<<dim3(D_MODEL / 32, D_MODEL / 32, 4), 256, 0, stream>>>(
        Wq, Wk, Wv, Wo, Wqt, Wkt, Wvt, Wot);

    gemm_qkv_k<<<dim3(576), 512, 0, stream>>>(
        query, key, value, Wqt, Wkt, Wvt, bq, bk, bv, qb, kb, vb);

    attn_mfma_k<<<dim3(768), 512, 0, stream>>>(qb, kb, vb, op, mlp);

    combine_k<<<dim3(MTOT * D_MODEL / 8 / 256), 256, 0, stream>>>(op, mlp, cb);

    gemm_o_k<<<dim3(768), 256, 0, stream>>>(cb, Wot, bo, out);
}

// Round 11
// 104.846 us; speedup vs baseline: 1.3209x; 1.0814x over previous
//
#include <hip/hip_runtime.h>
#include <hip/hip_bf16.h>
#include <math.h>

#define D_MODEL 768
#define HEADS 12
#define DK 64
#define SEQ 2048
#define BATCH 2
#define MTOT (BATCH * SEQ)   // 4096
#define QSCALE 0.18033688011112042f   // 0.125 * log2(e): softmax in exp2 domain

using short8 = __attribute__((ext_vector_type(8))) short;
using us4    = __attribute__((ext_vector_type(4))) unsigned short;
using f32x4  = __attribute__((ext_vector_type(4))) float;
using f32x16 = __attribute__((ext_vector_type(16))) float;

// ---------------- helpers ---------------------------------------------------
static __device__ __forceinline__ unsigned f2bf2(float x, float y) {
    __hip_bfloat162 t = __float22bfloat162_rn(float2{x, y});
    return *reinterpret_cast<unsigned*>(&t);
}
static __device__ __forceinline__ unsigned short f2bf1(float x) {
    __hip_bfloat16 t = __float2bfloat16(x);
    return *reinterpret_cast<unsigned short*>(&t);
}
static __device__ __forceinline__ float bf2f(unsigned short u) {
    unsigned v = (unsigned)u << 16;
    return __uint_as_float(v);
}
static __device__ __forceinline__ short8 cvt8(float4 a, float4 b) {
    union { unsigned u[4]; short8 s; } r;
    r.u[0] = f2bf2(a.x, a.y);
    r.u[1] = f2bf2(a.z, a.w);
    r.u[2] = f2bf2(b.x, b.y);
    r.u[3] = f2bf2(b.z, b.w);
    return r.s;
}
static __device__ __forceinline__ float fast_exp2(float x) {
#if __has_builtin(__builtin_amdgcn_exp2f)
    return __builtin_amdgcn_exp2f(x);
#else
    return __expf(x * 0.6931471805599453f);
#endif
}
// packed f32x2 -> bf16x2: d.lo16 = bf16(lo), d.hi16 = bf16(hi)
static __device__ __forceinline__ unsigned pk2(float lo, float hi) {
    unsigned d;
    asm("v_cvt_pk_bf16_f32 %0, %1, %2" : "=v"(d) : "v"(lo), "v"(hi));
    return d;
}

static __device__ __forceinline__ void gload_lds16(const void* g, void* l) {
    __builtin_amdgcn_global_load_lds(
        (const __attribute__((address_space(1))) void*)g,
        (__attribute__((address_space(3))) void*)l, 16, 0, 0);
}

static __device__ __forceinline__ void barrier_lgkm() {
    asm volatile("s_waitcnt lgkmcnt(0)" ::: "memory");
    __builtin_amdgcn_s_barrier();
    __builtin_amdgcn_sched_barrier(0);
}
static __device__ __forceinline__ void barrier_vm0() {
    asm volatile("s_waitcnt vmcnt(0)" ::: "memory");
    __builtin_amdgcn_s_barrier();
    __builtin_amdgcn_sched_barrier(0);
}

// ---------------- pre-pass: W[k][n] fp32 -> Wt[n][k] bf16 (4 W's fused) -----
__global__ __launch_bounds__(256) void cvt_wt_k(
    const float* __restrict__ Wq, const float* __restrict__ Wk,
    const float* __restrict__ Wv, const float* __restrict__ Wo,
    unsigned short* __restrict__ Wqt, unsigned short* __restrict__ Wkt,
    unsigned short* __restrict__ Wvt, unsigned short* __restrict__ Wot)
{
    const int z = blockIdx.z;
    const float* W = z == 0 ? Wq : z == 1 ? Wk : z == 2 ? Wv : Wo;
    unsigned short* Wt = z == 0 ? Wqt : z == 1 ? Wkt : z == 2 ? Wvt : Wot;
    __shared__ float t[32][33];
    const int n0 = blockIdx.x * 32, k0 = blockIdx.y * 32;
    const int tx = threadIdx.x & 31;
    const int ty0 = (threadIdx.x >> 5) * 4;
    #pragma unroll
    for (int j = 0; j < 4; ++j)
        t[ty0 + j][tx] = W[(size_t)(k0 + ty0 + j) * D_MODEL + n0 + tx];
    __syncthreads();
    #pragma unroll
    for (int j = 0; j < 4; ++j)
        Wt[(size_t)(n0 + ty0 + j) * D_MODEL + k0 + tx] = f2bf1(t[tx][ty0 + j]);
}

// ---- QKV GEMM: 128x128 tile, BK=64, 512 thr (8 waves 2x4), 2 bufs (R9) -----
__global__ __launch_bounds__(512) void gemm_qkv_k(
    const float* __restrict__ query, const float* __restrict__ key,
    const float* __restrict__ value,
    const unsigned short* __restrict__ Wqt, const unsigned short* __restrict__ Wkt,
    const unsigned short* __restrict__ Wvt,
    const float* __restrict__ bq, const float* __restrict__ bk,
    const float* __restrict__ bv,
    unsigned short* __restrict__ qb, unsigned short* __restrict__ kb,
    unsigned short* __restrict__ vb)
{
    __shared__ __align__(16) char gsm[65536];

    const int bid = blockIdx.x;
    const int xcd = bid & 7;
    const int idx = bid >> 3;          // 0..71
    const int z   = idx / 24;
    const int rr  = idx % 24;
    const int brow = (xcd * 4 + rr / 6) * 128;
    const int bcol = (rr % 6) * 128;

    const float* A           = z == 0 ? query : z == 1 ? key : value;
    const unsigned short* Wt = z == 0 ? Wqt : z == 1 ? Wkt : Wvt;
    const float* bias        = z == 0 ? bq  : z == 1 ? bk  : bv;
    unsigned short* C        = z == 0 ? qb  : z == 1 ? kb  : vb;
    const float scale        = z == 0 ? QSCALE : 1.0f;

    const int tid  = threadIdx.x;
    const int w    = tid >> 6;
    const int lane = tid & 63;
    const int g    = lane >> 4, c = lane & 15;
    const int wr   = w >> 2, wc = w & 3;

    f32x4 acc[4][2] = {};

    const int xc  = (c & 7) << 4;
    const int rb0 = c * 128 + ((g * 16) ^ xc);
    const int rb1 = c * 128 + ((64 + g * 16) ^ xc);

    int bsrow[2], bsoff[2], bsdst[2];
    #pragma unroll
    for (int r = 0; r < 2; ++r) {
        int phys = (w * 2 + r) * 1024 + lane * 16;
        int row  = phys >> 7;
        int slot = (phys >> 4) & 7;
        bsrow[r] = row;
        bsoff[r] = (slot ^ (row & 7)) * 8;
        bsdst[r] = (w * 2 + r) * 1024;
    }
    const int ar = tid >> 2;
    const int ac = (tid & 3) << 4;
    int awa[2];
    #pragma unroll
    for (int i = 0; i < 2; ++i)
        awa[i] = ar * 128 + (((ac << 1) + 16 * i) ^ ((ar & 7) << 4));
    const float* Ap32 = A + (size_t)(brow + ar) * D_MODEL + ac;

    float4 ra0, ra1, ra2, ra3;

    auto stageB = [&](int k0, int buf) {
        #pragma unroll
        for (int r = 0; r < 2; ++r)
            gload_lds16(Wt + (size_t)(bcol + bsrow[r]) * D_MODEL + k0 + bsoff[r],
                        gsm + 32768 + buf * 16384 + bsdst[r]);
    };
    auto loadA32 = [&](int k0) {
        ra0 = *(const float4*)(Ap32 + k0);
        ra1 = *(const float4*)(Ap32 + k0 + 4);
        ra2 = *(const float4*)(Ap32 + k0 + 8);
        ra3 = *(const float4*)(Ap32 + k0 + 12);
    };
    auto writeA32 = [&](int buf) {
        *(short8*)(gsm + buf * 16384 + awa[0]) = cvt8(ra0, ra1);
        *(short8*)(gsm + buf * 16384 + awa[1]) = cvt8(ra2, ra3);
    };

    stageB(0, 0);
    loadA32(0);
    writeA32(0);
    barrier_lgkm();

    for (int k0 = 0; k0 < D_MODEL; k0 += 128) {
        #pragma unroll
        for (int u = 0; u < 2; ++u) {
            const int kn = min(k0 + u * 64 + 64, D_MODEL - 64);
            stageB(kn, u ^ 1);
            loadA32(kn);
            __builtin_amdgcn_sched_barrier(0);

            __builtin_amdgcn_s_setprio(1);
            #pragma unroll
            for (int kstep = 0; kstep < 2; ++kstep) {
                const int rb = kstep ? rb1 : rb0;
                short8 af[4], bf[2];
                #pragma unroll
                for (int m = 0; m < 4; ++m)
                    af[m] = *(const short8*)(gsm + u * 16384 + wr * 8192 +
                                             m * 2048 + rb);
                #pragma unroll
                for (int n = 0; n < 2; ++n)
                    bf[n] = *(const short8*)(gsm + 32768 + u * 16384 +
                                             wc * 4096 + n * 2048 + rb);
                #pragma unroll
                for (int m = 0; m < 4; ++m)
                    #pragma unroll
                    for (int n = 0; n < 2; ++n)
                        acc[m][n] = __builtin_amdgcn_mfma_f32_16x16x32_bf16(
                                        af[m], bf[n], acc[m][n], 0, 0, 0);
            }
            __builtin_amdgcn_s_setprio(0);

            writeA32(u ^ 1);
            barrier_lgkm();
        }
    }

    #pragma unroll
    for (int m = 0; m < 4; ++m)
        #pragma unroll
        for (int n = 0; n < 2; ++n) {
            const int col = bcol + wc * 32 + n * 16 + c;
            const float bval = bias[col];
            #pragma unroll
            for (int j = 0; j < 4; ++j) {
                const int row = brow + wr * 64 + m * 16 + g * 4 + j;
                C[(size_t)row * D_MODEL + col] = f2bf1((acc[m][n][j] + bval) * scale);
            }
        }
}

// ---- O GEMM: 64x64 tile, BK=64, 256 thr, 2 bufs (R7/R9 proven) -------------
__global__ __launch_bounds__(256) void gemm_o_k(
    const unsigned short* __restrict__ A, const unsigned short* __restrict__ Wt,
    const float* __restrict__ bias, float* __restrict__ C)
{
    __shared__ __align__(16) char gsm[32768];

    const int bid = blockIdx.x;
    const int xcd = bid & 7;
    const int idx = bid >> 3;
    const int brow = (xcd * 8 + idx / 12) * 64;
    const int bcol = (idx % 12) * 64;

    const int tid  = threadIdx.x;
    const int w    = tid >> 6;
    const int lane = tid & 63;
    const int g    = lane >> 4, c = lane & 15;
    const int wr   = w >> 1, wc = w & 1;

    f32x4 acc[2][2] = {{f32x4{0,0,0,0}, f32x4{0,0,0,0}},
                       {f32x4{0,0,0,0}, f32x4{0,0,0,0}}};

    const int xc  = (c & 7) << 4;
    const int rb0 = c * 128 + ((g * 16) ^ xc);
    const int rb1 = c * 128 + ((64 + g * 16) ^ xc);
    const int a0 = rb0 + wr * 4096, a1 = rb1 + wr * 4096;
    const int b0r = rb0 + 16384 + wc * 4096, b1r = rb1 + 16384 + wc * 4096;

    int bsrow[2], bsoff[2], bsdst[2];
    #pragma unroll
    for (int r = 0; r < 2; ++r) {
        int phys = (w + 4 * r) * 1024 + lane * 16;
        int row  = phys >> 7;
        int slot = (phys >> 4) & 7;
        bsrow[r] = row;
        bsoff[r] = (slot ^ (row & 7)) * 8;
        bsdst[r] = (w + 4 * r) * 1024;
    }

    auto stage = [&](int k0, int buf) {
        #pragma unroll
        for (int r = 0; r < 2; ++r) {
            gload_lds16(A  + (size_t)(brow + bsrow[r]) * D_MODEL + k0 + bsoff[r],
                        gsm + buf * 8192 + bsdst[r]);
            gload_lds16(Wt + (size_t)(bcol + bsrow[r]) * D_MODEL + k0 + bsoff[r],
                        gsm + 16384 + buf * 8192 + bsdst[r]);
        }
    };

    stage(0, 0);
    barrier_vm0();

    for (int k0 = 0; k0 < D_MODEL; k0 += 128) {
        #pragma unroll
        for (int u = 0; u < 2; ++u) {
            const int kn = min(k0 + u * 64 + 64, D_MODEL - 64);
            stage(kn, u ^ 1);
            __builtin_amdgcn_sched_barrier(0);

            #pragma unroll
            for (int kstep = 0; kstep < 2; ++kstep) {
                short8 af[2], bf[2];
                #pragma unroll
                for (int m = 0; m < 2; ++m)
                    af[m] = *(const short8*)(gsm + u * 8192 + m * 2048 +
                                             (kstep ? a1 : a0));
                #pragma unroll
                for (int n = 0; n < 2; ++n)
                    bf[n] = *(const short8*)(gsm + u * 8192 + n * 2048 +
                                             (kstep ? b1r : b0r));
                #pragma unroll
                for (int m = 0; m < 2; ++m)
                    #pragma unroll
                    for (int n = 0; n < 2; ++n)
                        acc[m][n] = __builtin_amdgcn_mfma_f32_16x16x32_bf16(
                                        af[m], bf[n], acc[m][n], 0, 0, 0);
            }
            barrier_vm0();
        }
    }

    #pragma unroll
    for (int m = 0; m < 2; ++m)
        #pragma unroll
        for (int n = 0; n < 2; ++n) {
            const int col = bcol + wc * 32 + n * 16 + c;
            const float bval = bias[col];
            #pragma unroll
            for (int j = 0; j < 4; ++j) {
                const int row = brow + wr * 32 + m * 16 + g * 4 + j;
                C[(size_t)row * D_MODEL + col] = acc[m][n][j] + bval;
            }
        }
}

// ---------------- Flash attention: swapped 32x32 MFMA, in-register softmax --
// grid 768 (XCD-chunk swz), 256 thr = 4 waves; wave w owns q-rows [q0+32w, +32).
// KV-split x2 (half). S^T = mfma(K, Q): lane (c,hi), reg r holds
// S[key=(r&3)+8(r>>2)+4hi (+32 for s1)][qrow=c].
// Key permutation pi chosen so PV A-frags are LANE-LOCAL (no cross-lane ops):
//   pi(slot 16t+8hi+2j)   = 8t+4hi+j        (lo16 of frag word j, step t)
//   pi(slot 16t+8hi+2j+1) = 32+8t+4hi+j     (hi16)
// -> frag[t].word[j] = cvt_pk(s0[4t+j], s1[4t+j]).  V^T LDS stores key k at
// position pi^-1(k); staging thread cv writes {cv,cv+32} and {cv+16,cv+48} as
// two 4B words at pos P=16(cv>>3)+8((cv>>2)&1)+2(cv&3) and P+32 (addr ^64).
// Row-max cross-half reduce = one __shfl_xor(.,32). l via ONES-MFMA.
// LDS 32KB: K: 0+buf*8192 [key][d] swz ; V^T: 16384+buf*8192 [d][pos] swz.
__global__ __launch_bounds__(256) void attn_mfma_k(
    const unsigned short* __restrict__ q, const unsigned short* __restrict__ k,
    const unsigned short* __restrict__ v, unsigned short* __restrict__ opart,
    float* __restrict__ mpart, float* __restrict__ lpart)
{
    __shared__ __align__(16) char sm[32768];

    const int tid  = threadIdx.x;
    const int w    = tid >> 6;
    const int lane = tid & 63;
    const int c    = lane & 31;
    const int hi   = lane >> 5;

    const int bid  = blockIdx.x;
    const int swz  = (bid & 7) * 96 + (bid >> 3);
    const int qt   = swz & 15;
    const int rest = swz >> 4;
    const int half = rest & 1;
    const int hb   = rest >> 1;
    const int h    = hb % HEADS;
    const int b    = hb / HEADS;
    const int q0   = qt * 128;
    const int NT2  = 16;

    // Q B-frags (pre-scaled by QSCALE): lane (c,hi) holds Q[qrow=c][16t+8hi+i]
    short8 qf[4];
    {
        const unsigned short* qp =
            q + (size_t)(b * SEQ + q0 + w * 32 + c) * D_MODEL + h * DK;
        #pragma unroll
        for (int t = 0; t < 4; ++t)
            qf[t] = *(const short8*)(qp + t * 16 + hi * 8);
    }

    float m_run = -INFINITY;
    f32x16 lacc = {};
    f32x16 o0 = {}, o1 = {};
    const short8 ONES = {0x3F80, 0x3F80, 0x3F80, 0x3F80,
                         0x3F80, 0x3F80, 0x3F80, 0x3F80};

    // hoisted frag-read offsets: addr = base + c*128 + koff[t] (row&7 == c&7)
    const int xc = (c & 7) << 4;
    int koff[4];
    #pragma unroll
    for (int t = 0; t < 4; ++t)
        koff[t] = ((32 * t + 16 * hi) ^ xc) + c * 128;

    // K staging (linear dest + pre-swizzled source)
    int kdst[2];
    const unsigned short* kg[2];
    {
        const unsigned short* kbase =
            k + (size_t)(b * SEQ + half * (SEQ / 2)) * D_MODEL + h * DK;
        #pragma unroll
        for (int r = 0; r < 2; ++r) {
            int phys = (w + 4 * r) * 1024 + lane * 16;
            int row  = phys >> 7;
            int slot = (phys >> 4) & 7;
            kdst[r]  = (w + 4 * r) * 1024;
            kg[r]    = kbase + (size_t)row * D_MODEL + (slot ^ (row & 7)) * 8;
        }
    }
    // V staging (pi-permuted positions)
    const int cv = tid & 15, vd0 = (tid >> 4) << 2;
    const int vposP = 16 * (cv >> 3) + 8 * ((cv >> 2) & 1) + 2 * (cv & 3);
    int vwa[4];
    #pragma unroll
    for (int j = 0; j < 4; ++j) {
        const int row = vd0 + j;
        vwa[j] = 16384 + row * 128 + ((2 * vposP) ^ ((row & 7) << 4));
    }
    const unsigned short* vg =
        v + (size_t)(b * SEQ + half * (SEQ / 2) + cv) * D_MODEL + h * DK + vd0;
    const int TS = 64 * D_MODEL;

    us4 va, vb_, vc, vd;

    auto issue_k = [&](int buf) {
        gload_lds16(kg[0], sm + buf * 8192 + kdst[0]);
        gload_lds16(kg[1], sm + buf * 8192 + kdst[1]);
        kg[0] += TS; kg[1] += TS;
    };
    auto load_v = [&]() {
        va  = *(const us4*)(vg);
        vb_ = *(const us4*)(vg + 16 * D_MODEL);
        vc  = *(const us4*)(vg + 32 * D_MODEL);
        vd  = *(const us4*)(vg + 48 * D_MODEL);
        vg += TS;
    };
    auto write_v = [&](int buf) {
        #pragma unroll
        for (int j = 0; j < 4; ++j) {
            unsigned lo  = (unsigned)va[j]  | ((unsigned)vc[j] << 16);  // cv, cv+32
            unsigned hi2 = (unsigned)vb_[j] | ((unsigned)vd[j] << 16);  // cv+16, cv+48
            *(unsigned*)(sm + buf * 8192 + vwa[j])        = lo;
            *(unsigned*)(sm + buf * 8192 + (vwa[j] ^ 64)) = hi2;
        }
    };

    // prologue: tile 0
    issue_k(0);
    __builtin_amdgcn_sched_barrier(0);
    load_v();
    write_v(0);
    barrier_lgkm();

    for (int kt2 = 0; kt2 < NT2; kt2 += 2) {
        #pragma unroll
        for (int u = 0; u < 2; ++u) {
            const int tile = kt2 + u;
            // prefetch tile+1 (K before V: in-order vmcnt retirement invariant)
            issue_k(u ^ 1);
            __builtin_amdgcn_sched_barrier(0);
            load_v();
            __builtin_amdgcn_sched_barrier(0);

            // ---- S^T = K @ Q^T (2 key-halves x 4 d-steps) ----
            f32x16 s0 = {}, s1 = {};
            __builtin_amdgcn_s_setprio(1);
            #pragma unroll
            for (int t = 0; t < 4; ++t) {
                short8 kf0 = *(const short8*)(sm + u * 8192 + koff[t]);
                short8 kf1 = *(const short8*)(sm + u * 8192 + 4096 + koff[t]);
                s0 = __builtin_amdgcn_mfma_f32_32x32x16_bf16(kf0, qf[t], s0, 0, 0, 0);
                s1 = __builtin_amdgcn_mfma_f32_32x32x16_bf16(kf1, qf[t], s1, 0, 0, 0);
            }
            __builtin_amdgcn_s_setprio(0);

            // ---- row max (q-row = c): in-lane + one cross-half shfl ----
            float rmax = s0[0];
            #pragma unroll
            for (int r = 1; r < 16; ++r) rmax = fmaxf(rmax, s0[r]);
            #pragma unroll
            for (int r = 0; r < 16; ++r) rmax = fmaxf(rmax, s1[r]);
            rmax = fmaxf(rmax, __shfl_xor(rmax, 32));

            if (tile == 0) {
                m_run = rmax;
            } else if (__any(rmax > m_run + 11.0f)) {
                const float mnew = fmaxf(m_run, rmax);
                const float sc = fast_exp2(m_run - mnew);
                m_run = mnew;
                #pragma unroll
                for (int r = 0; r < 16; ++r) {
                    const float scr = __shfl(sc, (r & 3) + 8 * (r >> 2) + 4 * hi);
                    lacc[r] *= scr;
                    o0[r] *= scr;
                    o1[r] *= scr;
                }
            }

            // ---- P = exp2(S - m) in place ----
            #pragma unroll
            for (int r = 0; r < 16; ++r) {
                s0[r] = fast_exp2(s0[r] - m_run);
                s1[r] = fast_exp2(s1[r] - m_run);
            }

            // ---- PV: lane-local P frags (pi-matched), O += P@V, l += P@1 ----
            __builtin_amdgcn_s_setprio(1);
            #pragma unroll
            for (int t = 0; t < 4; ++t) {
                union { unsigned u4[4]; short8 s8; } pf;
                #pragma unroll
                for (int j = 0; j < 4; ++j)
                    pf.u4[j] = pk2(s0[4 * t + j], s1[4 * t + j]);
                short8 vf0 = *(const short8*)(sm + 16384 + u * 8192 + koff[t]);
                short8 vf1 = *(const short8*)(sm + 16384 + u * 8192 + 4096 + koff[t]);
                lacc = __builtin_amdgcn_mfma_f32_32x32x16_bf16(pf.s8, ONES, lacc, 0, 0, 0);
                o0 = __builtin_amdgcn_mfma_f32_32x32x16_bf16(pf.s8, vf0, o0, 0, 0, 0);
                o1 = __builtin_amdgcn_mfma_f32_32x32x16_bf16(pf.s8, vf1, o1, 0, 0, 0);
            }
            __builtin_amdgcn_s_setprio(0);

            // ---- V(next) regs -> LDS (reg-dep retires this tile's VMEM) ----
            write_v(u ^ 1);
            barrier_lgkm();
        }
    }

    // ---- store partials: o (bf16, unnormalized), m, l ----
    const size_t obase = (size_t)half * ((size_t)MTOT * D_MODEL) +
                         (size_t)(b * SEQ) * D_MODEL + h * DK;
    #pragma unroll
    for (int r = 0; r < 16; ++r) {
        const int qrow = q0 + w * 32 + (r & 3) + 8 * (r >> 2) + 4 * hi;
        unsigned short* ob = opart + obase + (size_t)qrow * D_MODEL;
        ob[c]      = f2bf1(o0[r]);
        ob[32 + c] = f2bf1(o1[r]);
    }
    const size_t mlbase = (size_t)half * MTOT * HEADS +
                          (size_t)(b * SEQ) * HEADS + h;
    if (hi == 0)
        mpart[mlbase + (size_t)(q0 + w * 32 + c) * HEADS] = m_run;
    if (c == 0) {
        #pragma unroll
        for (int r = 0; r < 16; ++r) {
            const int qrow = q0 + w * 32 + (r & 3) + 8 * (r >> 2) + 4 * hi;
            lpart[mlbase + (size_t)qrow * HEADS] = lacc[r];
        }
    }
}

// ---------------- combine: merge the two KV-halves exactly ------------------
__global__ __launch_bounds__(256) void combine_k(
    const unsigned short* __restrict__ op, const float* __restrict__ mp,
    const float* __restrict__ lp, unsigned short* __restrict__ cb)
{
    const int t   = blockIdx.x * 256 + threadIdx.x;
    const int row = t / 96;
    const int gi  = t - row * 96;
    const int col = gi << 3;
    const int h   = gi >> 3;

    const float m0 = mp[(size_t)row * HEADS + h];
    const float m1 = mp[(size_t)MTOT * HEADS + (size_t)row * HEADS + h];
    const float l0 = lp[(size_t)row * HEADS + h];
    const float l1 = lp[(size_t)MTOT * HEADS + (size_t)row * HEADS + h];
    const float m  = fmaxf(m0, m1);
    const float s0 = fast_exp2(m0 - m);
    const float s1 = fast_exp2(m1 - m);
    const float inv = 1.0f / (l0 * s0 + l1 * s1);
    const float a0 = s0 * inv, a1 = s1 * inv;

    const size_t off = (size_t)row * D_MODEL + col;
    us4 x0  = *(const us4*)(op + off);
    us4 x0b = *(const us4*)(op + off + 4);
    us4 x1  = *(const us4*)(op + (size_t)MTOT * D_MODEL + off);
    us4 x1b = *(const us4*)(op + (size_t)MTOT * D_MODEL + off + 4);

    union { unsigned short u[8]; short8 s; } r;
    #pragma unroll
    for (int j = 0; j < 4; ++j) {
        r.u[j]     = f2bf1(bf2f(x0[j])  * a0 + bf2f(x1[j])  * a1);
        r.u[4 + j] = f2bf1(bf2f(x0b[j]) * a0 + bf2f(x1b[j]) * a1);
    }
    *(short8*)(cb + off) = r.s;
}

// ---------------------------------------------------------------------------
extern "C" void kernel_launch(void* const* d_in, const int* in_sizes, int n_in,
                              void* d_out, int out_size, void* d_ws, size_t ws_size,
                              hipStream_t stream) {
    const float* query = (const float*)d_in[0];
    const float* key   = (const float*)d_in[1];
    const float* value = (const float*)d_in[2];
    const float* Wq = (const float*)d_in[3];
    const float* bq = (const float*)d_in[4];
    const float* Wk = (const float*)d_in[5];
    const float* bk = (const float*)d_in[6];
    const float* Wv = (const float*)d_in[7];
    const float* bv = (const float*)d_in[8];
    const float* Wo = (const float*)d_in[9];
    const float* bo = (const float*)d_in[10];
    float* out = (float*)d_out;

    const size_t mat = (size_t)MTOT * D_MODEL;      // 3.145M elems
    unsigned short* qb  = (unsigned short*)d_ws;    // projected Q/K/V (bf16)
    unsigned short* kb  = qb + mat;
    unsigned short* vb  = kb + mat;
    unsigned short* cb  = vb + mat;                 // combined context (bf16)
    unsigned short* Wqt = cb + mat;                 // transposed bf16 weights
    unsigned short* Wkt = Wqt + (size_t)D_MODEL * D_MODEL;
    unsigned short* Wvt = Wkt + (size_t)D_MODEL * D_MODEL;
    unsigned short* Wot = Wvt + (size_t)D_MODEL * D_MODEL;
    unsigned short* op  = Wot + (size_t)D_MODEL * D_MODEL;   // o partials x2
    float*          mp  = (float*)(op + 2 * mat);            // m partials x2
    float*          lp  = mp + 2 * (size_t)MTOT * HEADS;     // l partials x2

    cvt_wt_k<<<dim3(D_MODEL / 32, D_MODEL / 32, 4), 256, 0, stream>>>(
        Wq, Wk, Wv, Wo, Wqt, Wkt, Wvt, Wot);

    gemm_qkv_k<<<dim3(576), 512, 0, stream>>>(
        query, key, value, Wqt, Wkt, Wvt, bq, bk, bv, qb, kb, vb);

    attn_mfma_k<<<dim3(768), 256, 0, stream>>>(qb, kb, vb, op, mp, lp);

    combine_k<<<dim3(MTOT * D_MODEL / 8 / 256), 256, 0, stream>>>(op, mp, lp, cb);

    gemm_o_k<<<dim3(768), 256, 0, stream>>>(cb, Wot, bo, out);
}